// Round 8
// baseline (174.089 us; speedup 1.0000x reference)
//
#include <hip/hip_runtime.h>

// Problem constants (match reference)
#define BQ 512
#define AQ 32
#define DQ 256
#define NQ (BQ * AQ)      // 16384 nodes
#define EQ 1048576        // edges
#define THR 0.5f
#define EPSF 1e-5f
#define DEG_STRIDE 160    // per-target list cap; deg ~ Binom(E,1/N) mean 64, +12 sigma
#define BIN_TGTS 64       // targets per bin
#define NBINS (NQ / BIN_TGTS)          // 256
#define BIN_STRIDE 4864   // mean 4096 edges/bin, sigma ~64, +12 sigma

typedef __attribute__((ext_vector_type(8))) short bf16x8;
typedef __attribute__((ext_vector_type(4))) float f32x4;

// fp32 -> bf16 round-to-nearest-even (finite inputs)
__device__ __forceinline__ unsigned short f2bf(float f) {
    unsigned int u = __float_as_uint(f);
    return (unsigned short)((u + 0x7FFFu + ((u >> 16) & 1u)) >> 16);
}
__device__ __forceinline__ float bf2f(unsigned short h) {
    return __uint_as_float((unsigned int)h << 16);
}

// ---------------------------------------------------------------------------
// Dispatch 1 (768 blocks -> 3 blocks/CU; round-7 had 1/CU per slice):
//  blocks [0,256):    W [K,N] fp32 -> Wt hi/lo [N,K] bf16 split
//  blocks [256,768):  edge partition, 512 blocks x 2048 edges (8/thread)
// bin_cursor pre-zeroed by hipMemsetAsync.
// ---------------------------------------------------------------------------
__global__ __launch_bounds__(256) void k_wt_part(
        const float* __restrict__ W, unsigned short* __restrict__ Wt,
        const int* __restrict__ src, const int* __restrict__ tgt,
        int* __restrict__ bin_cursor, unsigned int* __restrict__ binned) {
    __shared__ int hist[NBINS];
    int tid = threadIdx.x;
    if (blockIdx.x < 256) {
        int idx = blockIdx.x * 256 + tid;       // covers DQ*DQ
        int n = idx >> 8;
        int k = idx & 255;
        float w = W[k * DQ + n];
        unsigned short h = f2bf(w);
        Wt[idx] = h;                            // hi plane
        Wt[DQ * DQ + idx] = f2bf(w - bf2f(h));  // lo plane
        return;
    }
    // ---- edge partition (round-6 scheme, half-size blocks) ----
    hist[tid] = 0;
    __syncthreads();
    int base = (blockIdx.x - 256) * 2048;
    int t[8], s[8];
    #pragma unroll
    for (int i = 0; i < 8; i++) {
        int e = base + i * 256 + tid;
        t[i] = tgt[e];
        s[i] = src[e];
        atomicAdd(&hist[t[i] >> 6], 1);
    }
    __syncthreads();
    int mine = hist[tid];
    __syncthreads();
    hist[tid] = tid * BIN_STRIDE + atomicAdd(&bin_cursor[tid], mine);
    __syncthreads();
    #pragma unroll
    for (int i = 0; i < 8; i++) {
        int slot = atomicAdd(&hist[t[i] >> 6], 1);
        binned[slot] = ((unsigned int)t[i] << 14) | (unsigned int)s[i];
    }
}

// ---------------------------------------------------------------------------
// Dispatch 2 (768 blocks):
//  blocks [0,512):    bf16x3 split MFMA GEMM, N-split: block = 64 M x 128 N.
//                     LDS stages 128 Wt rows/slab (20 KB, was 40), acc = 8
//                     fragments (32 VGPR, was 64). Same per-element MFMA
//                     chain -> bit-identical xwb. Adjacent blocks share A
//                     rows (L2 locality).
//  blocks [512,768):  per-bin degree count -> dinv (round-6 body).
// ---------------------------------------------------------------------------
__global__ __launch_bounds__(256) void k_gemm_cnt(
        const float* __restrict__ Xp, const unsigned short* __restrict__ Wt,
        unsigned short* __restrict__ xwb,
        const int* __restrict__ bin_cursor, const unsigned int* __restrict__ binned,
        float* __restrict__ dinv) {
    __shared__ unsigned short bs[2][128 * 40];   // 20 KB (gemm); cnt aliases 256B
    int tid = threadIdx.x;
    if (blockIdx.x >= 512) {
        // ---- per-bin degree count ----
        int* lcnt = (int*)&bs[0][0];
        int b = blockIdx.x - 512;
        if (tid < BIN_TGTS) lcnt[tid] = 0;
        __syncthreads();
        int beg = b * BIN_STRIDE;
        int count = bin_cursor[b];
        if (count > BIN_STRIDE) count = BIN_STRIDE;
        for (int i = beg + tid; i < beg + count; i += 256) {
            unsigned int ed = binned[i];
            atomicAdd(&lcnt[(ed >> 14) & 63], 1);
        }
        __syncthreads();
        if (tid < BIN_TGTS)
            dinv[b * BIN_TGTS + tid] = rsqrtf((float)(lcnt[tid] + 1));
        return;
    }
    // ---- bf16x3 split MFMA GEMM, N-split ----
    int mtile = blockIdx.x >> 1;      // 0..255
    int nbase = (blockIdx.x & 1) * 128;
    int wave = tid >> 6;
    int lane = tid & 63;
    int col = lane & 15;
    int quad = lane >> 4;
    int mbase = mtile * 64 + wave * 16;
    int m = mbase + col;

    const float* arow = Xp + (size_t)m * DQ;

    f32x4 acc[8];
    f32x4 zero = {0.f, 0.f, 0.f, 0.f};
    #pragma unroll
    for (int i = 0; i < 8; i++) acc[i] = zero;

    for (int k0 = 0; k0 < DQ; k0 += 32) {
        // ---- stage B half-slab: 128 rows x 32 k x 2 planes; 1 row-plane/thread
        __syncthreads();              // previous slab fully consumed
        {
            int row = tid & 127;
            int plane = tid >> 7;
            const uint4* g = (const uint4*)(Wt + (size_t)plane * DQ * DQ +
                                            (size_t)(nbase + row) * DQ + k0);
            uint4* l = (uint4*)&bs[plane][row * 40];
            #pragma unroll
            for (int u = 0; u < 4; u++) l[u] = g[u];
        }
        __syncthreads();

        int kq = k0 + quad * 8;
        float4 a0 = *(const float4*)(arow + kq);
        float4 a1 = *(const float4*)(arow + kq + 4);
        float av[8] = {a0.x, a0.y, a0.z, a0.w, a1.x, a1.y, a1.z, a1.w};
        bf16x8 ah, al;
        #pragma unroll
        for (int j = 0; j < 8; j++) {
            unsigned short h = f2bf(av[j]);
            ah[j] = (short)h;
            al[j] = (short)f2bf(av[j] - bf2f(h));
        }
        #pragma unroll
        for (int nt = 0; nt < 8; nt++) {
            int n = nt * 16 + col;
            bf16x8 bh = *(const bf16x8*)&bs[0][n * 40 + quad * 8];
            bf16x8 bl = *(const bf16x8*)&bs[1][n * 40 + quad * 8];
            acc[nt] = __builtin_amdgcn_mfma_f32_16x16x32_bf16(ah, bh, acc[nt], 0, 0, 0);
            acc[nt] = __builtin_amdgcn_mfma_f32_16x16x32_bf16(al, bh, acc[nt], 0, 0, 0);
            acc[nt] = __builtin_amdgcn_mfma_f32_16x16x32_bf16(ah, bl, acc[nt], 0, 0, 0);
        }
    }

    #pragma unroll
    for (int nt = 0; nt < 8; nt++) {
        #pragma unroll
        for (int r = 0; r < 4; r++) {
            xwb[(size_t)(mbase + quad * 4 + r) * DQ + nbase + nt * 16 + col] =
                f2bf(acc[nt][r]);
        }
    }
}

// ---------------------------------------------------------------------------
// Fused aggregation + scores — EXACT round-3/7 proven body (67us, VGPR 40):
// 512 thr, 8 waves, phase-0 LDS scatter of this clip's half-bin, round-0
// 8-deep gather inner loop, dinv array.
// ---------------------------------------------------------------------------
__global__ __launch_bounds__(512) void k_agg_scores(
        const unsigned int* __restrict__ xwb,
        const unsigned int* __restrict__ binned,
        const int* __restrict__ bin_cursor,
        const float* __restrict__ dinv,
        const float* __restrict__ bias,
        float* __restrict__ out,      // Xo [NQ*DQ]
        float* __restrict__ mask) {   // [BQ*AQ*AQ]
    __shared__ float xs[AQ][DQ + 4];   // 33 KB; rows 1040B = 65x16B aligned
    __shared__ float sq[AQ];
    __shared__ float sc[AQ][AQ + 1];
    __shared__ float rmin[AQ], rmax[AQ];
    __shared__ unsigned short lbuck[AQ * DEG_STRIDE];  // 10 KB
    __shared__ int lcnt[AQ];

    int tid = threadIdx.x;
    int wave = tid >> 6;              // 0..7
    int lane = tid & 63;
    int bq = blockIdx.x;              // batch clip
    const uint2* xw2 = (const uint2*)xwb;

    // ---- phase 0: scatter this clip's edges into per-actor LDS lists ----
    if (tid < AQ) lcnt[tid] = 0;
    __syncthreads();
    {
        int b = bq >> 1;              // bin covering clips {2b, 2b+1}
        int beg = b * BIN_STRIDE;
        int count = bin_cursor[b];
        if (count > BIN_STRIDE) count = BIN_STRIDE;
        for (int i = beg + tid; i < beg + count; i += 512) {
            unsigned int ed = binned[i];
            if ((int)(ed >> 19) == bq) {          // target's clip == mine
                int a = (ed >> 14) & 31;
                int pos = atomicAdd(&lcnt[a], 1);
                if (pos < DEG_STRIDE)
                    lbuck[a * DEG_STRIDE + pos] = (unsigned short)(ed & 0x3FFFu);
            }
        }
    }
    __syncthreads();

    float4 bv = ((const float4*)bias)[lane];

    // ---- phase 1: gather 4 targets per wave (round-0 inner loop) ----
    #pragma unroll 1
    for (int i = 0; i < 4; i++) {
        int a = wave * 4 + i;         // actor 0..31
        int t = bq * AQ + a;
        float dt = dinv[t];
        float c0 = dt * dt;
        uint2 sp = xw2[(size_t)t * 64 + lane];
        float4 acc;
        acc.x = __uint_as_float(sp.x << 16) * c0;
        acc.y = __uint_as_float(sp.x & 0xFFFF0000u) * c0;
        acc.z = __uint_as_float(sp.y << 16) * c0;
        acc.w = __uint_as_float(sp.y & 0xFFFF0000u) * c0;

        int num = lcnt[a];
        if (num > DEG_STRIDE) num = DEG_STRIDE;
        for (int k0 = 0; k0 < num; k0 += 64) {
            int rem = num - k0;
            int n = rem < 64 ? rem : 64;
            int idx = k0 + (lane < n ? lane : 0);
            int e = (int)lbuck[a * DEG_STRIDE + idx];   // LDS, 2-way free
            float cl = (lane < n) ? dinv[e] * dt : 0.f;
            int n8 = (n + 7) & ~7;
            for (int j0 = 0; j0 < n8; j0 += 8) {
                #pragma unroll
                for (int jj = 0; jj < 8; jj++) {
                    int j = j0 + jj;
                    int s = __shfl(e, j);
                    float c = __shfl(cl, j);
                    uint2 p = xw2[(size_t)s * 64 + lane];
                    acc.x += __uint_as_float(p.x << 16) * c;
                    acc.y += __uint_as_float(p.x & 0xFFFF0000u) * c;
                    acc.z += __uint_as_float(p.y << 16) * c;
                    acc.w += __uint_as_float(p.y & 0xFFFF0000u) * c;
                }
            }
        }

        acc.x += bv.x; acc.y += bv.y; acc.z += bv.z; acc.w += bv.w;
        ((float4*)out)[(size_t)t * 64 + lane] = acc;
        *(float4*)&xs[a][lane * 4] = acc;
    }
    __syncthreads();

    // ---- phase 2: scores (identical math to round 0) ----
    if (tid < AQ) {
        const float4* xi = (const float4*)xs[tid];
        float s = 0.f;
        #pragma unroll 8
        for (int dd = 0; dd < DQ / 4; dd++) {
            float4 a = xi[dd];
            s += a.x * a.x + a.y * a.y + a.z * a.z + a.w * a.w;
        }
        sq[tid] = s;
    }
    __syncthreads();

    {
        int p0 = tid * 2;             // 2 pairs per thread (1024 pairs)
        int i = p0 >> 5;
        int j0 = p0 & 31;
        const float4* xi = (const float4*)xs[i];
        float g[2] = {0.f, 0.f};
        for (int dd = 0; dd < DQ / 4; dd += 8) {
            float4 ar[8];
            #pragma unroll
            for (int u = 0; u < 8; u++) ar[u] = xi[dd + u];
            #pragma unroll
            for (int q = 0; q < 2; q++) {
                const float4* xj = (const float4*)xs[j0 + q];
                float gq = 0.f;
                #pragma unroll
                for (int u = 0; u < 8; u++) {
                    float4 b = xj[dd + u];
                    gq += ar[u].x * b.x + ar[u].y * b.y +
                          ar[u].z * b.z + ar[u].w * b.w;
                }
                g[q] += gq;
            }
        }
        #pragma unroll
        for (int q = 0; q < 2; q++) {
            sc[i][j0 + q] = sq[i] - 2.f * g[q] + sq[j0 + q];
        }
    }
    __syncthreads();

    if (tid < AQ) {
        float mn = sc[tid][0], mx = sc[tid][0];
        for (int j = 1; j < AQ; j++) {
            float v = sc[tid][j];
            mn = fminf(mn, v);
            mx = fmaxf(mx, v);
        }
        rmin[tid] = mn;
        rmax[tid] = mx;
    }
    __syncthreads();

    {
        float* mb = mask + (size_t)bq * AQ * AQ;
        int p0 = tid * 2;
        int i = p0 >> 5, j0 = p0 & 31;
        float inv = 1.0f / (rmax[i] - rmin[i] + EPSF);
        float2 mv;
        mv.x = ((sc[i][j0 + 0] - rmin[i]) * inv > THR) ? 1.0f : 0.0f;
        mv.y = ((sc[i][j0 + 1] - rmin[i]) * inv > THR) ? 1.0f : 0.0f;
        ((float2*)mb)[tid] = mv;
    }
}

// ---------------------------------------------------------------------------
extern "C" void kernel_launch(void* const* d_in, const int* in_sizes, int n_in,
                              void* d_out, int out_size, void* d_ws, size_t ws_size,
                              hipStream_t stream) {
    const float* X    = (const float*)d_in[0];   // [B,A,D]
    const int*   ei   = (const int*)d_in[1];     // [2,E]
    const float* W    = (const float*)d_in[2];   // [D,D]
    const float* bias = (const float*)d_in[3];   // [D]
    float* out = (float*)d_out;                  // [N*D] Xo  ++  [B*A*A] mask

    char* ws = (char*)d_ws;
    unsigned short* xwb = (unsigned short*)ws;                              // 8 MB
    unsigned int* binned = (unsigned int*)(ws + (size_t)NQ * DQ * 2);       // 4.98 MB
    unsigned short* Wt = (unsigned short*)(binned + (size_t)NBINS * BIN_STRIDE); // 512 KB
    float* dinv = (float*)(Wt + 2 * DQ * DQ);                               // 64 KB
    int* bin_cursor = (int*)(dinv + NQ);                                    // 1 KB

    const int* src = ei;
    const int* tgt = ei + EQ;

    hipMemsetAsync(bin_cursor, 0, NBINS * sizeof(int), stream);
    k_wt_part<<<768, 256, 0, stream>>>(W, Wt, src, tgt, bin_cursor, binned);
    k_gemm_cnt<<<768, 256, 0, stream>>>(X, Wt, xwb, bin_cursor, binned, dinv);
    k_agg_scores<<<BQ, 512, 0, stream>>>((const unsigned int*)xwb, binned,
                                         bin_cursor, dinv, bias, out,
                                         out + (size_t)NQ * DQ);
}

// Round 9
// 173.605 us; speedup vs baseline: 1.0028x; 1.0028x over previous
//
#include <hip/hip_runtime.h>

// Problem constants (match reference)
#define BQ 512
#define AQ 32
#define DQ 256
#define NQ (BQ * AQ)      // 16384 nodes
#define EQ 1048576        // edges
#define THR 0.5f
#define EPSF 1e-5f
#define DEG_STRIDE 160    // per-target list cap; deg ~ Binom(E,1/N) mean 64, +12 sigma
#define BIN_TGTS 64       // targets per bin
#define NBINS (NQ / BIN_TGTS)          // 256
#define BIN_STRIDE 4864   // mean 4096 edges/bin, sigma ~64, +12 sigma
#define NBLK_P 256        // partition blocks (count/scatter)
#define EPB (EQ / NBLK_P) // 4096 edges per partition block

typedef __attribute__((ext_vector_type(8))) short bf16x8;
typedef __attribute__((ext_vector_type(4))) float f32x4;

// fp32 -> bf16 round-to-nearest-even (finite inputs)
__device__ __forceinline__ unsigned short f2bf(float f) {
    unsigned int u = __float_as_uint(f);
    return (unsigned short)((u + 0x7FFFu + ((u >> 16) & 1u)) >> 16);
}
__device__ __forceinline__ float bf2f(unsigned short h) {
    return __uint_as_float((unsigned int)h << 16);
}

// ---------------------------------------------------------------------------
// Dispatch 1:
//  blocks [0,256):    W [K,N] fp32 -> Wt hi/lo [N,K] bf16 split
//  blocks [256,512):  per-block bin COUNT: LDS histogram of 4096 edges ->
//                     cntT[bin][blk] (plain stores — no global atomics, no
//                     memset needed).
// ---------------------------------------------------------------------------
__global__ __launch_bounds__(256) void k_wt_count(
        const float* __restrict__ W, unsigned short* __restrict__ Wt,
        const int* __restrict__ tgt, int* __restrict__ cntT) {
    __shared__ int hist[NBINS];
    int tid = threadIdx.x;
    if (blockIdx.x < 256) {
        int idx = blockIdx.x * 256 + tid;       // covers DQ*DQ
        int n = idx >> 8;
        int k = idx & 255;
        float w = W[k * DQ + n];
        unsigned short h = f2bf(w);
        Wt[idx] = h;                            // hi plane
        Wt[DQ * DQ + idx] = f2bf(w - bf2f(h));  // lo plane
        return;
    }
    int b = blockIdx.x - 256;
    hist[tid] = 0;
    __syncthreads();
    int base = b * EPB;
    #pragma unroll
    for (int i = 0; i < 16; i++) {
        int t = tgt[base + i * 256 + tid];
        atomicAdd(&hist[t >> 6], 1);
    }
    __syncthreads();
    cntT[tid * NBLK_P + b] = hist[tid];         // [bin][blk]
}

// ---------------------------------------------------------------------------
// Dispatch 2:
//  blocks [0,256):    SCAN: bin b — coalesced row read of cntT[b][*], 8-step
//                     LDS Hillis-Steele prefix over the 256 block counts ->
//                     baseT[b][k] = b*BIN_STRIDE + excl_prefix(k); total ->
//                     bin_cursor[b]. Replaces the 512-deep same-address
//                     device-atomic reservation chains (the round-8 theory
//                     for the occupancy-insensitive ~60-75us front end).
//  blocks [256,768):  bf16x3 split MFMA GEMM, N-split (EXACT round-8 body;
//                     bit-identical xwb).
// ---------------------------------------------------------------------------
__global__ __launch_bounds__(256) void k_scan_gemm(
        const float* __restrict__ Xp, const unsigned short* __restrict__ Wt,
        unsigned short* __restrict__ xwb,
        const int* __restrict__ cntT, int* __restrict__ baseT,
        int* __restrict__ bin_cursor) {
    __shared__ unsigned short bs[2][128 * 40];   // 20 KB (gemm); scan aliases 1KB
    int tid = threadIdx.x;
    if (blockIdx.x < 256) {
        // ---- scan for bin b ----
        int* sdat = (int*)&bs[0][0];
        int b = blockIdx.x;
        int v = cntT[b * NBLK_P + tid];
        sdat[tid] = v;
        __syncthreads();
        #pragma unroll
        for (int off = 1; off < 256; off <<= 1) {
            int add = (tid >= off) ? sdat[tid - off] : 0;
            __syncthreads();
            sdat[tid] += add;
            __syncthreads();
        }
        int incl = sdat[tid];
        baseT[b * NBLK_P + tid] = b * BIN_STRIDE + (incl - v);
        if (tid == 255) bin_cursor[b] = incl;
        return;
    }
    // ---- bf16x3 split MFMA GEMM, N-split (EXACT round-8 body) ----
    int bx = blockIdx.x - 256;
    int mtile = bx >> 1;              // 0..255
    int nbase = (bx & 1) * 128;
    int wave = tid >> 6;
    int lane = tid & 63;
    int col = lane & 15;
    int quad = lane >> 4;
    int mbase = mtile * 64 + wave * 16;
    int m = mbase + col;

    const float* arow = Xp + (size_t)m * DQ;

    f32x4 acc[8];
    f32x4 zero = {0.f, 0.f, 0.f, 0.f};
    #pragma unroll
    for (int i = 0; i < 8; i++) acc[i] = zero;

    for (int k0 = 0; k0 < DQ; k0 += 32) {
        __syncthreads();              // previous slab fully consumed
        {
            int row = tid & 127;
            int plane = tid >> 7;
            const uint4* g = (const uint4*)(Wt + (size_t)plane * DQ * DQ +
                                            (size_t)(nbase + row) * DQ + k0);
            uint4* l = (uint4*)&bs[plane][row * 40];
            #pragma unroll
            for (int u = 0; u < 4; u++) l[u] = g[u];
        }
        __syncthreads();

        int kq = k0 + quad * 8;
        float4 a0 = *(const float4*)(arow + kq);
        float4 a1 = *(const float4*)(arow + kq + 4);
        float av[8] = {a0.x, a0.y, a0.z, a0.w, a1.x, a1.y, a1.z, a1.w};
        bf16x8 ah, al;
        #pragma unroll
        for (int j = 0; j < 8; j++) {
            unsigned short h = f2bf(av[j]);
            ah[j] = (short)h;
            al[j] = (short)f2bf(av[j] - bf2f(h));
        }
        #pragma unroll
        for (int nt = 0; nt < 8; nt++) {
            int n = nt * 16 + col;
            bf16x8 bh = *(const bf16x8*)&bs[0][n * 40 + quad * 8];
            bf16x8 bl = *(const bf16x8*)&bs[1][n * 40 + quad * 8];
            acc[nt] = __builtin_amdgcn_mfma_f32_16x16x32_bf16(ah, bh, acc[nt], 0, 0, 0);
            acc[nt] = __builtin_amdgcn_mfma_f32_16x16x32_bf16(al, bh, acc[nt], 0, 0, 0);
            acc[nt] = __builtin_amdgcn_mfma_f32_16x16x32_bf16(ah, bl, acc[nt], 0, 0, 0);
        }
    }

    #pragma unroll
    for (int nt = 0; nt < 8; nt++) {
        #pragma unroll
        for (int r = 0; r < 4; r++) {
            xwb[(size_t)(mbase + quad * 4 + r) * DQ + nbase + nt * 16 + col] =
                f2bf(acc[nt][r]);
        }
    }
}

// ---------------------------------------------------------------------------
// Dispatch 3: deterministic SCATTER. Re-read edges; LDS cursor per bin seeded
// from baseT[*][blk]; slot = LDS atomicAdd (no global atomics). Same binned
// layout/semantics as all previous rounds.
// ---------------------------------------------------------------------------
__global__ __launch_bounds__(256) void k_scatter(
        const int* __restrict__ src, const int* __restrict__ tgt,
        const int* __restrict__ baseT, unsigned int* __restrict__ binned) {
    __shared__ int lcur[NBINS];
    int tid = threadIdx.x;
    int b = blockIdx.x;
    lcur[tid] = baseT[tid * NBLK_P + b];   // column read, L2-hot from scan
    __syncthreads();
    int base = b * EPB;
    int t[16], s[16];
    #pragma unroll
    for (int i = 0; i < 16; i++) {
        int e = base + i * 256 + tid;
        t[i] = tgt[e];
        s[i] = src[e];
    }
    #pragma unroll
    for (int i = 0; i < 16; i++) {
        int slot = atomicAdd(&lcur[t[i] >> 6], 1);
        binned[slot] = ((unsigned int)t[i] << 14) | (unsigned int)s[i];
    }
}

// ---------------------------------------------------------------------------
// Dispatch 4: per-bin degree count -> dinv (EXACT round-8 body).
// ---------------------------------------------------------------------------
__global__ __launch_bounds__(256) void k_cnt(
        const int* __restrict__ bin_cursor, const unsigned int* __restrict__ binned,
        float* __restrict__ dinv) {
    __shared__ int lcnt[BIN_TGTS];
    int tid = threadIdx.x;
    int b = blockIdx.x;
    if (tid < BIN_TGTS) lcnt[tid] = 0;
    __syncthreads();
    int beg = b * BIN_STRIDE;
    int count = bin_cursor[b];
    if (count > BIN_STRIDE) count = BIN_STRIDE;
    for (int i = beg + tid; i < beg + count; i += 256) {
        unsigned int ed = binned[i];
        atomicAdd(&lcnt[(ed >> 14) & 63], 1);
    }
    __syncthreads();
    if (tid < BIN_TGTS)
        dinv[b * BIN_TGTS + tid] = rsqrtf((float)(lcnt[tid] + 1));
}

// ---------------------------------------------------------------------------
// Fused aggregation + scores — EXACT round-3/8 proven body (67us, VGPR 40).
// ---------------------------------------------------------------------------
__global__ __launch_bounds__(512) void k_agg_scores(
        const unsigned int* __restrict__ xwb,
        const unsigned int* __restrict__ binned,
        const int* __restrict__ bin_cursor,
        const float* __restrict__ dinv,
        const float* __restrict__ bias,
        float* __restrict__ out,      // Xo [NQ*DQ]
        float* __restrict__ mask) {   // [BQ*AQ*AQ]
    __shared__ float xs[AQ][DQ + 4];   // 33 KB; rows 1040B = 65x16B aligned
    __shared__ float sq[AQ];
    __shared__ float sc[AQ][AQ + 1];
    __shared__ float rmin[AQ], rmax[AQ];
    __shared__ unsigned short lbuck[AQ * DEG_STRIDE];  // 10 KB
    __shared__ int lcnt[AQ];

    int tid = threadIdx.x;
    int wave = tid >> 6;              // 0..7
    int lane = tid & 63;
    int bq = blockIdx.x;              // batch clip
    const uint2* xw2 = (const uint2*)xwb;

    // ---- phase 0: scatter this clip's edges into per-actor LDS lists ----
    if (tid < AQ) lcnt[tid] = 0;
    __syncthreads();
    {
        int b = bq >> 1;              // bin covering clips {2b, 2b+1}
        int beg = b * BIN_STRIDE;
        int count = bin_cursor[b];
        if (count > BIN_STRIDE) count = BIN_STRIDE;
        for (int i = beg + tid; i < beg + count; i += 512) {
            unsigned int ed = binned[i];
            if ((int)(ed >> 19) == bq) {          // target's clip == mine
                int a = (ed >> 14) & 31;
                int pos = atomicAdd(&lcnt[a], 1);
                if (pos < DEG_STRIDE)
                    lbuck[a * DEG_STRIDE + pos] = (unsigned short)(ed & 0x3FFFu);
            }
        }
    }
    __syncthreads();

    float4 bv = ((const float4*)bias)[lane];

    // ---- phase 1: gather 4 targets per wave (round-0 inner loop) ----
    #pragma unroll 1
    for (int i = 0; i < 4; i++) {
        int a = wave * 4 + i;         // actor 0..31
        int t = bq * AQ + a;
        float dt = dinv[t];
        float c0 = dt * dt;
        uint2 sp = xw2[(size_t)t * 64 + lane];
        float4 acc;
        acc.x = __uint_as_float(sp.x << 16) * c0;
        acc.y = __uint_as_float(sp.x & 0xFFFF0000u) * c0;
        acc.z = __uint_as_float(sp.y << 16) * c0;
        acc.w = __uint_as_float(sp.y & 0xFFFF0000u) * c0;

        int num = lcnt[a];
        if (num > DEG_STRIDE) num = DEG_STRIDE;
        for (int k0 = 0; k0 < num; k0 += 64) {
            int rem = num - k0;
            int n = rem < 64 ? rem : 64;
            int idx = k0 + (lane < n ? lane : 0);
            int e = (int)lbuck[a * DEG_STRIDE + idx];   // LDS, 2-way free
            float cl = (lane < n) ? dinv[e] * dt : 0.f;
            int n8 = (n + 7) & ~7;
            for (int j0 = 0; j0 < n8; j0 += 8) {
                #pragma unroll
                for (int jj = 0; jj < 8; jj++) {
                    int j = j0 + jj;
                    int s = __shfl(e, j);
                    float c = __shfl(cl, j);
                    uint2 p = xw2[(size_t)s * 64 + lane];
                    acc.x += __uint_as_float(p.x << 16) * c;
                    acc.y += __uint_as_float(p.x & 0xFFFF0000u) * c;
                    acc.z += __uint_as_float(p.y << 16) * c;
                    acc.w += __uint_as_float(p.y & 0xFFFF0000u) * c;
                }
            }
        }

        acc.x += bv.x; acc.y += bv.y; acc.z += bv.z; acc.w += bv.w;
        ((float4*)out)[(size_t)t * 64 + lane] = acc;
        *(float4*)&xs[a][lane * 4] = acc;
    }
    __syncthreads();

    // ---- phase 2: scores (identical math to round 0) ----
    if (tid < AQ) {
        const float4* xi = (const float4*)xs[tid];
        float s = 0.f;
        #pragma unroll 8
        for (int dd = 0; dd < DQ / 4; dd++) {
            float4 a = xi[dd];
            s += a.x * a.x + a.y * a.y + a.z * a.z + a.w * a.w;
        }
        sq[tid] = s;
    }
    __syncthreads();

    {
        int p0 = tid * 2;             // 2 pairs per thread (1024 pairs)
        int i = p0 >> 5;
        int j0 = p0 & 31;
        const float4* xi = (const float4*)xs[i];
        float g[2] = {0.f, 0.f};
        for (int dd = 0; dd < DQ / 4; dd += 8) {
            float4 ar[8];
            #pragma unroll
            for (int u = 0; u < 8; u++) ar[u] = xi[dd + u];
            #pragma unroll
            for (int q = 0; q < 2; q++) {
                const float4* xj = (const float4*)xs[j0 + q];
                float gq = 0.f;
                #pragma unroll
                for (int u = 0; u < 8; u++) {
                    float4 b = xj[dd + u];
                    gq += ar[u].x * b.x + ar[u].y * b.y +
                          ar[u].z * b.z + ar[u].w * b.w;
                }
                g[q] += gq;
            }
        }
        #pragma unroll
        for (int q = 0; q < 2; q++) {
            sc[i][j0 + q] = sq[i] - 2.f * g[q] + sq[j0 + q];
        }
    }
    __syncthreads();

    if (tid < AQ) {
        float mn = sc[tid][0], mx = sc[tid][0];
        for (int j = 1; j < AQ; j++) {
            float v = sc[tid][j];
            mn = fminf(mn, v);
            mx = fmaxf(mx, v);
        }
        rmin[tid] = mn;
        rmax[tid] = mx;
    }
    __syncthreads();

    {
        float* mb = mask + (size_t)bq * AQ * AQ;
        int p0 = tid * 2;
        int i = p0 >> 5, j0 = p0 & 31;
        float inv = 1.0f / (rmax[i] - rmin[i] + EPSF);
        float2 mv;
        mv.x = ((sc[i][j0 + 0] - rmin[i]) * inv > THR) ? 1.0f : 0.0f;
        mv.y = ((sc[i][j0 + 1] - rmin[i]) * inv > THR) ? 1.0f : 0.0f;
        ((float2*)mb)[tid] = mv;
    }
}

// ---------------------------------------------------------------------------
extern "C" void kernel_launch(void* const* d_in, const int* in_sizes, int n_in,
                              void* d_out, int out_size, void* d_ws, size_t ws_size,
                              hipStream_t stream) {
    const float* X    = (const float*)d_in[0];   // [B,A,D]
    const int*   ei   = (const int*)d_in[1];     // [2,E]
    const float* W    = (const float*)d_in[2];   // [D,D]
    const float* bias = (const float*)d_in[3];   // [D]
    float* out = (float*)d_out;                  // [N*D] Xo  ++  [B*A*A] mask

    char* ws = (char*)d_ws;
    unsigned short* xwb = (unsigned short*)ws;                              // 8 MB
    unsigned int* binned = (unsigned int*)(ws + (size_t)NQ * DQ * 2);       // 4.98 MB
    unsigned short* Wt = (unsigned short*)(binned + (size_t)NBINS * BIN_STRIDE); // 256 KB
    float* dinv = (float*)(Wt + 2 * DQ * DQ);                               // 64 KB
    int* bin_cursor = (int*)(dinv + NQ);                                    // 1 KB
    int* cntT = bin_cursor + NBINS;                                         // 256 KB
    int* baseT = cntT + NBINS * NBLK_P;                                     // 256 KB

    const int* src = ei;
    const int* tgt = ei + EQ;

    k_wt_count<<<512, 256, 0, stream>>>(W, Wt, tgt, cntT);
    k_scan_gemm<<<768, 256, 0, stream>>>(X, Wt, xwb, cntT, baseT, bin_cursor);
    k_scatter<<<NBLK_P, 256, 0, stream>>>(src, tgt, baseT, binned);
    k_cnt<<<256, 256, 0, stream>>>(bin_cursor, binned, dinv);
    k_agg_scores<<<BQ, 512, 0, stream>>>((const unsigned int*)xwb, binned,
                                         bin_cursor, dinv, bias, out,
                                         out + (size_t)NQ * DQ);
}